// Round 1
// baseline (1623.543 us; speedup 1.0000x reference)
//
#include <hip/hip_runtime.h>
#include <hip/hip_bf16.h>
#include <math.h>

constexpr int B_ = 4, L_ = 2048, IN_DIM = 3072, DM = 128, DI = 256, DS = 16, NL = 6;
constexpr int ROWS = B_ * L_; // 8192

static __device__ __forceinline__ float silu_f(float x) {
  return x / (1.f + __expf(-x));
}

// ---------------- generic tiled fp32 GEMM: C = A@B (+bias) ----------------
// BM=64, BN=64, BK=16, 256 threads, 4x4 micro-tile
__global__ __launch_bounds__(256) void gemm_f32(const float* __restrict__ A,
                                                const float* __restrict__ Bv,
                                                const float* __restrict__ bias,
                                                float* __restrict__ C,
                                                int M, int N, int K) {
  constexpr int BM = 64, BN = 64, BK = 16;
  __shared__ float As[BK][BM + 4];
  __shared__ float Bs[BK][BN + 4];
  int tid = threadIdx.x;
  int tm = tid / 16, tn = tid % 16;
  int bm = blockIdx.y * BM, bn = blockIdx.x * BN;
  float acc[4][4] = {};
  for (int k0 = 0; k0 < K; k0 += BK) {
    for (int i = tid; i < BM * BK; i += 256) {
      int r = i / BK, c = i % BK;
      As[c][r] = A[(size_t)(bm + r) * K + k0 + c];
    }
    for (int i = tid; i < BK * BN; i += 256) {
      int r = i / BN, c = i % BN;
      Bs[r][c] = Bv[(size_t)(k0 + r) * N + bn + c];
    }
    __syncthreads();
#pragma unroll
    for (int kk = 0; kk < BK; ++kk) {
      float4 a4 = *(const float4*)&As[kk][tm * 4];
      float4 b4 = *(const float4*)&Bs[kk][tn * 4];
      float a[4] = {a4.x, a4.y, a4.z, a4.w};
      float b[4] = {b4.x, b4.y, b4.z, b4.w};
#pragma unroll
      for (int i = 0; i < 4; ++i)
#pragma unroll
        for (int j = 0; j < 4; ++j) acc[i][j] = fmaf(a[i], b[j], acc[i][j]);
    }
    __syncthreads();
  }
  float bb[4];
#pragma unroll
  for (int j = 0; j < 4; ++j) bb[j] = bias ? bias[bn + tn * 4 + j] : 0.f;
#pragma unroll
  for (int i = 0; i < 4; ++i) {
    int r = bm + tm * 4 + i;
    float4 o;
    o.x = acc[i][0] + bb[0];
    o.y = acc[i][1] + bb[1];
    o.z = acc[i][2] + bb[2];
    o.w = acc[i][3] + bb[3];
    *(float4*)&C[(size_t)r * N + bn + tn * 4] = o;
  }
}

// ---------------- rmsnorm over rows of 128 ----------------
__global__ __launch_bounds__(256) void rmsnorm_kernel(const float* __restrict__ x,
                                                      const float* __restrict__ w,
                                                      float* __restrict__ out) {
  int wave = threadIdx.x >> 6, lane = threadIdx.x & 63;
  int row = blockIdx.x * 4 + wave;
  float2 v = *(const float2*)(x + (size_t)row * DM + 2 * lane);
  float ss = v.x * v.x + v.y * v.y;
#pragma unroll
  for (int o = 32; o >= 1; o >>= 1) ss += __shfl_xor(ss, o);
  float rs = 1.f / sqrtf(ss * (1.f / 128.f) + 1e-5f);
  float2 wv = *(const float2*)(w + 2 * lane);
  float2 o2;
  o2.x = v.x * rs * wv.x;
  o2.y = v.y * rs * wv.y;
  *(float2*)(out + (size_t)row * DM + 2 * lane) = o2;
}

// ---------------- causal depthwise conv (k=4) + bias + silu ----------------
// writes xs in row layout [row][c] and transposed [b*DI+c][l]
__global__ __launch_bounds__(256) void conv_silu_kernel(const float* __restrict__ xz,
                                                        const float* __restrict__ conv_w,
                                                        const float* __restrict__ conv_b,
                                                        float* __restrict__ xs_row,
                                                        float* __restrict__ xs_T) {
  __shared__ float tile[64][65];
  __shared__ float cw[64][4];
  __shared__ float cb[64];
  int b = blockIdx.z, l0 = blockIdx.y * 64, c0 = blockIdx.x * 64;
  int tid = threadIdx.x;
  cw[tid / 4][tid % 4] = conv_w[(size_t)c0 * 4 + tid];
  if (tid < 64) cb[tid] = conv_b[c0 + tid];
  __syncthreads();
  int cl = tid % 64;
  int lbase = tid / 64;  // 0..3
#pragma unroll
  for (int i = 0; i < 16; ++i) {
    int ll = lbase + 4 * i;
    int l = l0 + ll;
    float acc = cb[cl];
#pragma unroll
    for (int k = 0; k < 4; ++k) {
      int li = l + k - 3;
      if (li >= 0) acc = fmaf(xz[((size_t)(b * L_ + li)) * 512 + c0 + cl], cw[cl][k], acc);
    }
    tile[ll][cl] = silu_f(acc);
  }
  __syncthreads();
  for (int i = tid; i < 4096; i += 256) {
    int lr = i / 64, c = i % 64;
    xs_row[((size_t)(b * L_ + l0 + lr)) * DI + c0 + c] = tile[lr][c];
  }
  for (int i = tid; i < 4096; i += 256) {
    int c = i / 64, lr = i % 64;
    xs_T[((size_t)(b * DI + c0 + c)) * L_ + l0 + lr] = tile[lr][c];
  }
}

// ---------------- dbl = xs @ W_x  (256 -> 40) ----------------
__global__ __launch_bounds__(256) void dbl_kernel(const float* __restrict__ xs_row,
                                                  const float* __restrict__ W_x,
                                                  float* __restrict__ dbl) {
  __shared__ float Xs[64][257];
  __shared__ float Wx[256 * 40];
  int tid = threadIdx.x;
  int r0 = blockIdx.x * 64;
  for (int i = tid; i < 64 * 256; i += 256) {
    int r = i >> 8, k = i & 255;
    Xs[r][k] = xs_row[(size_t)(r0 + r) * DI + k];
  }
  for (int i = tid; i < 256 * 40; i += 256) Wx[i] = W_x[i];
  __syncthreads();
  int r = tid & 63, q = tid >> 6;  // q in 0..3 -> output cols q*10..q*10+9
  float acc[10] = {};
  for (int k = 0; k < 256; ++k) {
    float v = Xs[r][k];
#pragma unroll
    for (int j = 0; j < 10; ++j) acc[j] = fmaf(v, Wx[k * 40 + q * 10 + j], acc[j]);
  }
#pragma unroll
  for (int j = 0; j < 10; ++j) dbl[(size_t)(r0 + r) * 40 + q * 10 + j] = acc[j];
}

// ---------------- delta = softplus(dt @ W_dt + b_dt), stored transposed ----------------
__global__ __launch_bounds__(256) void delta_kernel(const float* __restrict__ dbl,
                                                    const float* __restrict__ W_dt,
                                                    const float* __restrict__ b_dt,
                                                    float* __restrict__ delta_T) {
  __shared__ float Tile[64][257];
  __shared__ float Dt[64][8];
  __shared__ float Wdt[8 * 256];
  int tid = threadIdx.x;
  int r0 = blockIdx.x * 64;
  int b = r0 / L_, l0 = r0 % L_;
  for (int i = tid; i < 64 * 8; i += 256) {
    int r = i >> 3, k = i & 7;
    Dt[r][k] = dbl[(size_t)(r0 + r) * 40 + k];
  }
  for (int i = tid; i < 8 * 256; i += 256) Wdt[i] = W_dt[i];
  __syncthreads();
  int c = tid;  // 0..255
  float bd = b_dt[c];
  for (int r = 0; r < 64; ++r) {
    float a = bd;
#pragma unroll
    for (int k = 0; k < 8; ++k) a = fmaf(Dt[r][k], Wdt[k * 256 + c], a);
    float sp = (a > 20.f) ? a : log1pf(__expf(a));
    Tile[r][c] = sp;
  }
  __syncthreads();
  for (int i = tid; i < 64 * 256; i += 256) {
    int cc = i >> 6, rr = i & 63;
    delta_T[((size_t)(b * DI + cc)) * L_ + l0 + rr] = Tile[rr][cc];
  }
}

// ---------------- selective scan: 16 lanes (states) per (b,c) ----------------
__global__ __launch_bounds__(64) void scan_kernel(const float* __restrict__ delta_T,
                                                  const float* __restrict__ xs_T,
                                                  const float* __restrict__ dbl,
                                                  const float* __restrict__ A_log,
                                                  float* __restrict__ y) {
  int tid = threadIdx.x;
  int grp = tid >> 4, s = tid & 15;
  int g = blockIdx.x * 4 + grp;  // b*256 + c
  int b = g >> 8, c = g & 255;
  float A = -__expf(A_log[c * DS + s]);
  const float* dp = delta_T + (size_t)g * L_;
  const float* xp = xs_T + (size_t)g * L_;
  const float* bp = dbl + (size_t)b * L_ * 40 + 8 + s;
  const float* cp = dbl + (size_t)b * L_ * 40 + 24 + s;
  float* yp = y + (size_t)b * L_ * DI + c;
  float h = 0.f;
  for (int l = 0; l < L_; l += 4) {
    float4 d4 = *(const float4*)(dp + l);
    float4 x4 = *(const float4*)(xp + l);
    float dj[4] = {d4.x, d4.y, d4.z, d4.w};
    float xj[4] = {x4.x, x4.y, x4.z, x4.w};
#pragma unroll
    for (int j = 0; j < 4; ++j) {
      int li = l + j;
      float Bv = bp[(size_t)li * 40];
      float Cv = cp[(size_t)li * 40];
      float dA = __expf(dj[j] * A);
      h = fmaf(dA, h, dj[j] * Bv * xj[j]);
      float p = h * Cv;
      p += __shfl_xor(p, 8, 16);
      p += __shfl_xor(p, 4, 16);
      p += __shfl_xor(p, 2, 16);
      p += __shfl_xor(p, 1, 16);
      if (s == 0) yp[(size_t)li * DI] = p;
    }
  }
}

// ---------------- y = (y + xs*Dp) * silu(res) ----------------
__global__ __launch_bounds__(256) void ypost_kernel(float* __restrict__ y,
                                                    const float* __restrict__ xs_row,
                                                    const float* __restrict__ xz,
                                                    const float* __restrict__ Dp) {
  int idx = (blockIdx.x * 256 + threadIdx.x) * 4;
  int row = idx >> 8, c = idx & 255;
  float4 yv = *(float4*)(y + idx);
  float4 xv = *(const float4*)(xs_row + idx);
  float4 rv = *(const float4*)(xz + (size_t)row * 512 + 256 + c);
  float4 dv = *(const float4*)(Dp + c);
  yv.x = (yv.x + xv.x * dv.x) * silu_f(rv.x);
  yv.y = (yv.y + xv.y * dv.y) * silu_f(rv.y);
  yv.z = (yv.z + xv.z * dv.z) * silu_f(rv.z);
  yv.w = (yv.w + xv.w * dv.w) * silu_f(rv.w);
  *(float4*)(y + idx) = yv;
}

// ---------------- final: ob = y@W_out; h=h0+ob; rmsnorm; head; softmax; argmax ----------------
__global__ __launch_bounds__(256) void final_kernel(const float* __restrict__ y,
                                                    const float* __restrict__ W_out,
                                                    const float* __restrict__ h0,
                                                    const float* __restrict__ normf_w,
                                                    const float* __restrict__ W_head,
                                                    const float* __restrict__ b_head,
                                                    float* __restrict__ pi_out,
                                                    float* __restrict__ pred_out) {
  __shared__ float Wl[256 * 128];
  __shared__ float Wh[128 * 6];
  int tid = threadIdx.x;
  for (int i = tid; i < 256 * 128; i += 256) Wl[i] = W_out[i];
  for (int i = tid; i < 768; i += 256) Wh[i] = W_head[i];
  __syncthreads();
  int wave = tid >> 6, lane = tid & 63;
  float nw0 = normf_w[2 * lane], nw1 = normf_w[2 * lane + 1];
  float bh[6];
#pragma unroll
  for (int j = 0; j < 6; ++j) bh[j] = b_head[j];
  for (int ri = 0; ri < 8; ++ri) {
    int row = blockIdx.x * 32 + wave * 8 + ri;
    float acc0 = 0.f, acc1 = 0.f;
    for (int k = 0; k < 256; k += 4) {
      float4 yv = *(const float4*)(y + (size_t)row * DI + k);
      float vj[4] = {yv.x, yv.y, yv.z, yv.w};
#pragma unroll
      for (int j = 0; j < 4; ++j) {
        float2 w = *(const float2*)&Wl[(k + j) * 128 + 2 * lane];
        acc0 = fmaf(vj[j], w.x, acc0);
        acc1 = fmaf(vj[j], w.y, acc1);
      }
    }
    float hv0 = h0[(size_t)row * DM + 2 * lane] + acc0;
    float hv1 = h0[(size_t)row * DM + 2 * lane + 1] + acc1;
    float ss = hv0 * hv0 + hv1 * hv1;
#pragma unroll
    for (int o = 32; o >= 1; o >>= 1) ss += __shfl_xor(ss, o);
    float rs = 1.f / sqrtf(ss * (1.f / 128.f) + 1e-5f);
    float f0 = hv0 * rs * nw0, f1 = hv1 * rs * nw1;
    float lg[6];
#pragma unroll
    for (int j = 0; j < 6; ++j)
      lg[j] = f0 * Wh[(2 * lane) * 6 + j] + f1 * Wh[(2 * lane + 1) * 6 + j];
#pragma unroll
    for (int j = 0; j < 6; ++j) {
#pragma unroll
      for (int o = 32; o >= 1; o >>= 1) lg[j] += __shfl_xor(lg[j], o);
      lg[j] += bh[j];
    }
    if (lane == 0) {
      float mv = lg[0];
      int am = 0;
#pragma unroll
      for (int j = 1; j < 6; ++j)
        if (lg[j] > mv) { mv = lg[j]; am = j; }
      float e[6], sum = 0.f;
#pragma unroll
      for (int j = 0; j < 6; ++j) { e[j] = __expf(lg[j] - mv); sum += e[j]; }
      float inv = 1.f / sum;
#pragma unroll
      for (int j = 0; j < 6; ++j) pi_out[(size_t)row * NL + j] = e[j] * inv;
      pred_out[row] = (float)am;
    }
  }
}

extern "C" void kernel_launch(void* const* d_in, const int* in_sizes, int n_in,
                              void* d_out, int out_size, void* d_ws, size_t ws_size,
                              hipStream_t stream) {
  const float* x = (const float*)d_in[0];
  const float* W_emb = (const float*)d_in[1];
  const float* b_emb = (const float*)d_in[2];
  const float* norm_w = (const float*)d_in[3];
  const float* W_in = (const float*)d_in[4];
  const float* conv_w = (const float*)d_in[5];
  const float* conv_b = (const float*)d_in[6];
  const float* W_x = (const float*)d_in[7];
  const float* W_dt = (const float*)d_in[8];
  const float* b_dt = (const float*)d_in[9];
  const float* A_log = (const float*)d_in[10];
  const float* Dp = (const float*)d_in[11];
  const float* W_out = (const float*)d_in[12];
  const float* normf_w = (const float*)d_in[13];
  const float* W_head = (const float*)d_in[14];
  const float* b_head = (const float*)d_in[15];

  float* ws = (float*)d_ws;
  float* h0 = ws;                      // 8192*128
  float* u = h0 + 1048576;             // 8192*128
  float* xz = u + 1048576;             // 8192*512
  float* xs_row = xz + 4194304;        // 8192*256
  float* xs_T = xs_row + 2097152;      // 1024*2048
  float* dbl = xs_T + 2097152;         // 8192*40
  float* delta_T = dbl + 327680;       // 1024*2048
  float* y = delta_T + 2097152;        // 8192*256

  float* pi_out = (float*)d_out;
  float* pred_out = pi_out + (size_t)ROWS * NL;

  // 1) h0 = x @ W_emb + b_emb
  gemm_f32<<<dim3(2, 128), 256, 0, stream>>>(x, W_emb, b_emb, h0, ROWS, DM, IN_DIM);
  // 2) u = rmsnorm(h0)
  rmsnorm_kernel<<<2048, 256, 0, stream>>>(h0, norm_w, u);
  // 3) xz = u @ W_in
  gemm_f32<<<dim3(8, 128), 256, 0, stream>>>(u, W_in, nullptr, xz, ROWS, 2 * DI, DM);
  // 4) xs = silu(causal_dwconv(xz[:, :256]))
  conv_silu_kernel<<<dim3(4, 32, 4), 256, 0, stream>>>(xz, conv_w, conv_b, xs_row, xs_T);
  // 5) dbl = xs @ W_x
  dbl_kernel<<<128, 256, 0, stream>>>(xs_row, W_x, dbl);
  // 6) delta = softplus(dt @ W_dt + b_dt)  (transposed store)
  delta_kernel<<<128, 256, 0, stream>>>(dbl, W_dt, b_dt, delta_T);
  // 7) selective scan
  scan_kernel<<<256, 64, 0, stream>>>(delta_T, xs_T, dbl, A_log, y);
  // 8) y = (y + xs*Dp) * silu(res)
  ypost_kernel<<<2048, 256, 0, stream>>>(y, xs_row, xz, Dp);
  // 9) out GEMM + residual + rmsnorm + head + softmax + argmax
  final_kernel<<<256, 256, 0, stream>>>(y, W_out, h0, normf_w, W_head, b_head, pi_out, pred_out);
}

// Round 3
// 948.444 us; speedup vs baseline: 1.7118x; 1.7118x over previous
//
#include <hip/hip_runtime.h>
#include <hip/hip_bf16.h>
#include <math.h>

constexpr int B_ = 4, L_ = 2048, IN_DIM = 3072, DM = 128, DI = 256, DS = 16, NL = 6;
constexpr int ROWS = B_ * L_; // 8192

static __device__ __forceinline__ float silu_f(float x) {
  return x / (1.f + __expf(-x));
}

// ---------------- generic tiled fp32 GEMM: C = A@B (+bias) ----------------
// BM=64, BN=64, BK=16, 256 threads, 4x4 micro-tile
__global__ __launch_bounds__(256) void gemm_f32(const float* __restrict__ A,
                                                const float* __restrict__ Bv,
                                                const float* __restrict__ bias,
                                                float* __restrict__ C,
                                                int M, int N, int K) {
  constexpr int BM = 64, BN = 64, BK = 16;
  __shared__ float As[BK][BM + 4];
  __shared__ float Bs[BK][BN + 4];
  int tid = threadIdx.x;
  int tm = tid / 16, tn = tid % 16;
  int bm = blockIdx.y * BM, bn = blockIdx.x * BN;
  float acc[4][4] = {};
  for (int k0 = 0; k0 < K; k0 += BK) {
    for (int i = tid; i < BM * BK; i += 256) {
      int r = i / BK, c = i % BK;
      As[c][r] = A[(size_t)(bm + r) * K + k0 + c];
    }
    for (int i = tid; i < BK * BN; i += 256) {
      int r = i / BN, c = i % BN;
      Bs[r][c] = Bv[(size_t)(k0 + r) * N + bn + c];
    }
    __syncthreads();
#pragma unroll
    for (int kk = 0; kk < BK; ++kk) {
      float4 a4 = *(const float4*)&As[kk][tm * 4];
      float4 b4 = *(const float4*)&Bs[kk][tn * 4];
      float a[4] = {a4.x, a4.y, a4.z, a4.w};
      float b[4] = {b4.x, b4.y, b4.z, b4.w};
#pragma unroll
      for (int i = 0; i < 4; ++i)
#pragma unroll
        for (int j = 0; j < 4; ++j) acc[i][j] = fmaf(a[i], b[j], acc[i][j]);
    }
    __syncthreads();
  }
  float bb[4];
#pragma unroll
  for (int j = 0; j < 4; ++j) bb[j] = bias ? bias[bn + tn * 4 + j] : 0.f;
#pragma unroll
  for (int i = 0; i < 4; ++i) {
    int r = bm + tm * 4 + i;
    float4 o;
    o.x = acc[i][0] + bb[0];
    o.y = acc[i][1] + bb[1];
    o.z = acc[i][2] + bb[2];
    o.w = acc[i][3] + bb[3];
    *(float4*)&C[(size_t)r * N + bn + tn * 4] = o;
  }
}

// ---------------- rmsnorm over rows of 128 ----------------
__global__ __launch_bounds__(256) void rmsnorm_kernel(const float* __restrict__ x,
                                                      const float* __restrict__ w,
                                                      float* __restrict__ out) {
  int wave = threadIdx.x >> 6, lane = threadIdx.x & 63;
  int row = blockIdx.x * 4 + wave;
  float2 v = *(const float2*)(x + (size_t)row * DM + 2 * lane);
  float ss = v.x * v.x + v.y * v.y;
#pragma unroll
  for (int o = 32; o >= 1; o >>= 1) ss += __shfl_xor(ss, o);
  float rs = 1.f / sqrtf(ss * (1.f / 128.f) + 1e-5f);
  float2 wv = *(const float2*)(w + 2 * lane);
  float2 o2;
  o2.x = v.x * rs * wv.x;
  o2.y = v.y * rs * wv.y;
  *(float2*)(out + (size_t)row * DM + 2 * lane) = o2;
}

// ---------------- causal depthwise conv (k=4) + bias + silu ----------------
// writes xs in row layout [row][c] and transposed [b*DI+c][l]
__global__ __launch_bounds__(256) void conv_silu_kernel(const float* __restrict__ xz,
                                                        const float* __restrict__ conv_w,
                                                        const float* __restrict__ conv_b,
                                                        float* __restrict__ xs_row,
                                                        float* __restrict__ xs_T) {
  __shared__ float tile[64][65];
  __shared__ float cw[64][4];
  __shared__ float cb[64];
  int b = blockIdx.z, l0 = blockIdx.y * 64, c0 = blockIdx.x * 64;
  int tid = threadIdx.x;
  cw[tid / 4][tid % 4] = conv_w[(size_t)c0 * 4 + tid];
  if (tid < 64) cb[tid] = conv_b[c0 + tid];
  __syncthreads();
  int cl = tid % 64;
  int lbase = tid / 64;  // 0..3
#pragma unroll
  for (int i = 0; i < 16; ++i) {
    int ll = lbase + 4 * i;
    int l = l0 + ll;
    float acc = cb[cl];
#pragma unroll
    for (int k = 0; k < 4; ++k) {
      int li = l + k - 3;
      if (li >= 0) acc = fmaf(xz[((size_t)(b * L_ + li)) * 512 + c0 + cl], cw[cl][k], acc);
    }
    tile[ll][cl] = silu_f(acc);
  }
  __syncthreads();
  for (int i = tid; i < 4096; i += 256) {
    int lr = i / 64, c = i % 64;
    xs_row[((size_t)(b * L_ + l0 + lr)) * DI + c0 + c] = tile[lr][c];
  }
  for (int i = tid; i < 4096; i += 256) {
    int c = i / 64, lr = i % 64;
    xs_T[((size_t)(b * DI + c0 + c)) * L_ + l0 + lr] = tile[lr][c];
  }
}

// ---------------- dbl = xs @ W_x  (256 -> 40) ----------------
__global__ __launch_bounds__(256) void dbl_kernel(const float* __restrict__ xs_row,
                                                  const float* __restrict__ W_x,
                                                  float* __restrict__ dbl) {
  __shared__ float Xs[64][257];
  __shared__ float Wx[256 * 40];
  int tid = threadIdx.x;
  int r0 = blockIdx.x * 64;
  for (int i = tid; i < 64 * 256; i += 256) {
    int r = i >> 8, k = i & 255;
    Xs[r][k] = xs_row[(size_t)(r0 + r) * DI + k];
  }
  for (int i = tid; i < 256 * 40; i += 256) Wx[i] = W_x[i];
  __syncthreads();
  int r = tid & 63, q = tid >> 6;  // q in 0..3 -> output cols q*10..q*10+9
  float acc[10] = {};
  for (int k = 0; k < 256; ++k) {
    float v = Xs[r][k];
#pragma unroll
    for (int j = 0; j < 10; ++j) acc[j] = fmaf(v, Wx[k * 40 + q * 10 + j], acc[j]);
  }
#pragma unroll
  for (int j = 0; j < 10; ++j) dbl[(size_t)(r0 + r) * 40 + q * 10 + j] = acc[j];
}

// ---------------- delta = softplus(dt @ W_dt + b_dt), stored transposed ----------------
__global__ __launch_bounds__(256) void delta_kernel(const float* __restrict__ dbl,
                                                    const float* __restrict__ W_dt,
                                                    const float* __restrict__ b_dt,
                                                    float* __restrict__ delta_T) {
  __shared__ float Tile[64][257];
  __shared__ float Dt[64][8];
  __shared__ float Wdt[8 * 256];
  int tid = threadIdx.x;
  int r0 = blockIdx.x * 64;
  int b = r0 / L_, l0 = r0 % L_;
  for (int i = tid; i < 64 * 8; i += 256) {
    int r = i >> 3, k = i & 7;
    Dt[r][k] = dbl[(size_t)(r0 + r) * 40 + k];
  }
  for (int i = tid; i < 8 * 256; i += 256) Wdt[i] = W_dt[i];
  __syncthreads();
  int c = tid;  // 0..255
  float bd = b_dt[c];
  for (int r = 0; r < 64; ++r) {
    float a = bd;
#pragma unroll
    for (int k = 0; k < 8; ++k) a = fmaf(Dt[r][k], Wdt[k * 256 + c], a);
    float sp = (a > 20.f) ? a : log1pf(__expf(a));
    Tile[r][c] = sp;
  }
  __syncthreads();
  for (int i = tid; i < 64 * 256; i += 256) {
    int cc = i >> 6, rr = i & 63;
    delta_T[((size_t)(b * DI + cc)) * L_ + l0 + rr] = Tile[rr][cc];
  }
}

// ---------------- chunked parallel selective scan ----------------
// One block per (b,c): 512 threads = 32 chunks x 16 states, chunk length 64.
// Phase 1: per-chunk transfer (aprod = prod dA, hend = h from zero).
// Phase 2: 16 threads compose 32 chunk summaries -> exact h_start per chunk.
// Phase 3: replay each chunk from h_start, reduce h*C over 16 states -> y.
__global__ __launch_bounds__(512) void scan_kernel(const float* __restrict__ delta_T,
                                                   const float* __restrict__ xs_T,
                                                   const float* __restrict__ dbl,
                                                   const float* __restrict__ A_log,
                                                   float* __restrict__ y) {
  __shared__ float s_aprod[32][16];
  __shared__ float s_hend[32][16];
  __shared__ float s_hstart[32][16];
  int tid = threadIdx.x;
  int k = tid >> 4, s = tid & 15;   // chunk, state
  int g = blockIdx.x;               // b*256 + c
  int b = g >> 8, c = g & 255;
  float A = -__expf(A_log[c * DS + s]);
  const float* dp = delta_T + (size_t)g * L_ + k * 64;
  const float* xp = xs_T + (size_t)g * L_ + k * 64;
  const float* bp = dbl + ((size_t)(b * L_ + k * 64)) * 40 + 8 + s;
  const float* cp = dbl + ((size_t)(b * L_ + k * 64)) * 40 + 24 + s;

  // phase 1: chunk transfer function
  float aprod = 1.f, h = 0.f;
  for (int j = 0; j < 64; j += 4) {
    float4 d4 = *(const float4*)(dp + j);
    float4 x4 = *(const float4*)(xp + j);
    float dj[4] = {d4.x, d4.y, d4.z, d4.w};
    float xj[4] = {x4.x, x4.y, x4.z, x4.w};
#pragma unroll
    for (int u = 0; u < 4; ++u) {
      float Bv = bp[(size_t)(j + u) * 40];
      float dA = __expf(dj[u] * A);
      aprod *= dA;
      h = fmaf(dA, h, dj[u] * Bv * xj[u]);
    }
  }
  s_aprod[k][s] = aprod;
  s_hend[k][s] = h;
  __syncthreads();

  // phase 2: serial compose over chunks (16 threads, one per state)
  if (tid < 16) {
    float hh = 0.f;
    for (int kk = 0; kk < 32; ++kk) {
      s_hstart[kk][tid] = hh;
      hh = fmaf(s_aprod[kk][tid], hh, s_hend[kk][tid]);
    }
  }
  __syncthreads();

  // phase 3: replay chunk from exact start state, emit y
  h = s_hstart[k][s];
  float* yp = y + ((size_t)(b * L_) + k * 64) * DI + c;
  for (int j = 0; j < 64; j += 4) {
    float4 d4 = *(const float4*)(dp + j);
    float4 x4 = *(const float4*)(xp + j);
    float dj[4] = {d4.x, d4.y, d4.z, d4.w};
    float xj[4] = {x4.x, x4.y, x4.z, x4.w};
#pragma unroll
    for (int u = 0; u < 4; ++u) {
      float Bv = bp[(size_t)(j + u) * 40];
      float Cv = cp[(size_t)(j + u) * 40];
      float dA = __expf(dj[u] * A);
      h = fmaf(dA, h, dj[u] * Bv * xj[u]);
      float p = h * Cv;
      p += __shfl_xor(p, 8, 16);
      p += __shfl_xor(p, 4, 16);
      p += __shfl_xor(p, 2, 16);
      p += __shfl_xor(p, 1, 16);
      if (s == 0) yp[(size_t)(j + u) * DI] = p;
    }
  }
}

// ---------------- y = (y + xs*Dp) * silu(res) ----------------
__global__ __launch_bounds__(256) void ypost_kernel(float* __restrict__ y,
                                                    const float* __restrict__ xs_row,
                                                    const float* __restrict__ xz,
                                                    const float* __restrict__ Dp) {
  int idx = (blockIdx.x * 256 + threadIdx.x) * 4;
  int row = idx >> 8, c = idx & 255;
  float4 yv = *(float4*)(y + idx);
  float4 xv = *(const float4*)(xs_row + idx);
  float4 rv = *(const float4*)(xz + (size_t)row * 512 + 256 + c);
  float4 dv = *(const float4*)(Dp + c);
  yv.x = (yv.x + xv.x * dv.x) * silu_f(rv.x);
  yv.y = (yv.y + xv.y * dv.y) * silu_f(rv.y);
  yv.z = (yv.z + xv.z * dv.z) * silu_f(rv.z);
  yv.w = (yv.w + xv.w * dv.w) * silu_f(rv.w);
  *(float4*)(y + idx) = yv;
}

// ---------------- final: ob = y@W_out; h=h0+ob; rmsnorm; head; softmax; argmax ----------------
__global__ __launch_bounds__(256) void final_kernel(const float* __restrict__ y,
                                                    const float* __restrict__ W_out,
                                                    const float* __restrict__ h0,
                                                    const float* __restrict__ normf_w,
                                                    const float* __restrict__ W_head,
                                                    const float* __restrict__ b_head,
                                                    float* __restrict__ pi_out,
                                                    float* __restrict__ pred_out) {
  __shared__ float Wl[256 * 128];
  __shared__ float Wh[128 * 6];
  int tid = threadIdx.x;
  for (int i = tid; i < 256 * 128; i += 256) Wl[i] = W_out[i];
  for (int i = tid; i < 768; i += 256) Wh[i] = W_head[i];
  __syncthreads();
  int wave = tid >> 6, lane = tid & 63;
  float nw0 = normf_w[2 * lane], nw1 = normf_w[2 * lane + 1];
  float bh[6];
#pragma unroll
  for (int j = 0; j < 6; ++j) bh[j] = b_head[j];
  for (int ri = 0; ri < 8; ++ri) {
    int row = blockIdx.x * 32 + wave * 8 + ri;
    float acc0 = 0.f, acc1 = 0.f;
    for (int k = 0; k < 256; k += 4) {
      float4 yv = *(const float4*)(y + (size_t)row * DI + k);
      float vj[4] = {yv.x, yv.y, yv.z, yv.w};
#pragma unroll
      for (int j = 0; j < 4; ++j) {
        float2 w = *(const float2*)&Wl[(k + j) * 128 + 2 * lane];
        acc0 = fmaf(vj[j], w.x, acc0);
        acc1 = fmaf(vj[j], w.y, acc1);
      }
    }
    float hv0 = h0[(size_t)row * DM + 2 * lane] + acc0;
    float hv1 = h0[(size_t)row * DM + 2 * lane + 1] + acc1;
    float ss = hv0 * hv0 + hv1 * hv1;
#pragma unroll
    for (int o = 32; o >= 1; o >>= 1) ss += __shfl_xor(ss, o);
    float rs = 1.f / sqrtf(ss * (1.f / 128.f) + 1e-5f);
    float f0 = hv0 * rs * nw0, f1 = hv1 * rs * nw1;
    float lg[6];
#pragma unroll
    for (int j = 0; j < 6; ++j)
      lg[j] = f0 * Wh[(2 * lane) * 6 + j] + f1 * Wh[(2 * lane + 1) * 6 + j];
#pragma unroll
    for (int j = 0; j < 6; ++j) {
#pragma unroll
      for (int o = 32; o >= 1; o >>= 1) lg[j] += __shfl_xor(lg[j], o);
      lg[j] += bh[j];
    }
    if (lane == 0) {
      float mv = lg[0];
      int am = 0;
#pragma unroll
      for (int j = 1; j < 6; ++j)
        if (lg[j] > mv) { mv = lg[j]; am = j; }
      float e[6], sum = 0.f;
#pragma unroll
      for (int j = 0; j < 6; ++j) { e[j] = __expf(lg[j] - mv); sum += e[j]; }
      float inv = 1.f / sum;
#pragma unroll
      for (int j = 0; j < 6; ++j) pi_out[(size_t)row * NL + j] = e[j] * inv;
      pred_out[row] = (float)am;
    }
  }
}

extern "C" void kernel_launch(void* const* d_in, const int* in_sizes, int n_in,
                              void* d_out, int out_size, void* d_ws, size_t ws_size,
                              hipStream_t stream) {
  const float* x = (const float*)d_in[0];
  const float* W_emb = (const float*)d_in[1];
  const float* b_emb = (const float*)d_in[2];
  const float* norm_w = (const float*)d_in[3];
  const float* W_in = (const float*)d_in[4];
  const float* conv_w = (const float*)d_in[5];
  const float* conv_b = (const float*)d_in[6];
  const float* W_x = (const float*)d_in[7];
  const float* W_dt = (const float*)d_in[8];
  const float* b_dt = (const float*)d_in[9];
  const float* A_log = (const float*)d_in[10];
  const float* Dp = (const float*)d_in[11];
  const float* W_out = (const float*)d_in[12];
  const float* normf_w = (const float*)d_in[13];
  const float* W_head = (const float*)d_in[14];
  const float* b_head = (const float*)d_in[15];

  float* ws = (float*)d_ws;
  float* h0 = ws;                      // 8192*128
  float* u = h0 + 1048576;             // 8192*128
  float* xz = u + 1048576;             // 8192*512
  float* xs_row = xz + 4194304;        // 8192*256
  float* xs_T = xs_row + 2097152;      // 1024*2048
  float* dbl = xs_T + 2097152;         // 8192*40
  float* delta_T = dbl + 327680;       // 1024*2048
  float* y = delta_T + 2097152;        // 8192*256

  float* pi_out = (float*)d_out;
  float* pred_out = pi_out + (size_t)ROWS * NL;

  // 1) h0 = x @ W_emb + b_emb
  gemm_f32<<<dim3(2, 128), 256, 0, stream>>>(x, W_emb, b_emb, h0, ROWS, DM, IN_DIM);
  // 2) u = rmsnorm(h0)
  rmsnorm_kernel<<<2048, 256, 0, stream>>>(h0, norm_w, u);
  // 3) xz = u @ W_in
  gemm_f32<<<dim3(8, 128), 256, 0, stream>>>(u, W_in, nullptr, xz, ROWS, 2 * DI, DM);
  // 4) xs = silu(causal_dwconv(xz[:, :256]))
  conv_silu_kernel<<<dim3(4, 32, 4), 256, 0, stream>>>(xz, conv_w, conv_b, xs_row, xs_T);
  // 5) dbl = xs @ W_x
  dbl_kernel<<<128, 256, 0, stream>>>(xs_row, W_x, dbl);
  // 6) delta = softplus(dt @ W_dt + b_dt)  (transposed store)
  delta_kernel<<<128, 256, 0, stream>>>(dbl, W_dt, b_dt, delta_T);
  // 7) chunked parallel selective scan
  scan_kernel<<<1024, 512, 0, stream>>>(delta_T, xs_T, dbl, A_log, y);
  // 8) y = (y + xs*Dp) * silu(res)
  ypost_kernel<<<2048, 256, 0, stream>>>(y, xs_row, xz, Dp);
  // 9) out GEMM + residual + rmsnorm + head + softmax + argmax
  final_kernel<<<256, 256, 0, stream>>>(y, W_out, h0, normf_w, W_head, b_head, pi_out, pred_out);
}

// Round 4
// 448.886 us; speedup vs baseline: 3.6168x; 2.1129x over previous
//
#include <hip/hip_runtime.h>
#include <hip/hip_bf16.h>
#include <math.h>

constexpr int B_ = 4, L_ = 2048, IN_DIM = 3072, DM = 128, DI = 256, DS = 16, NL = 6;
constexpr int ROWS = B_ * L_; // 8192
constexpr int SPLITK = 8, KC = IN_DIM / SPLITK; // 384

static __device__ __forceinline__ float silu_f(float x) {
  return x / (1.f + __expf(-x));
}

// ---------------- split-K embedding GEMM: part[s] = x[:, sKC:(s+1)KC] @ W_emb[sKC:(s+1)KC, :] ----
// BM=64, BN=128 (full N), BK=16, 256 threads, 4x8 micro-tile
__global__ __launch_bounds__(256) void gemm_emb_splitk(const float* __restrict__ A,
                                                       const float* __restrict__ Bv,
                                                       float* __restrict__ part) {
  constexpr int BM = 64, BN = 128, BK = 16;
  __shared__ float As[BK][BM + 4];
  __shared__ float Bs[BK][BN + 4];
  int split = blockIdx.x;          // 0..7
  int bm = blockIdx.y * BM;        // row block
  int kb = split * KC;
  int tid = threadIdx.x;
  int tm = tid >> 4, tn = tid & 15;  // 16x16 thread grid
  float acc[4][8] = {};
  for (int k0 = 0; k0 < KC; k0 += BK) {
    // A tile 64x16: each thread one float4 along K
    {
      int r = tid >> 2, kq = (tid & 3) * 4;
      float4 a4 = *(const float4*)&A[(size_t)(bm + r) * IN_DIM + kb + k0 + kq];
      As[kq + 0][r] = a4.x;
      As[kq + 1][r] = a4.y;
      As[kq + 2][r] = a4.z;
      As[kq + 3][r] = a4.w;
    }
    // B tile 16x128: each thread two float4
    {
      int r = tid >> 5, c = (tid & 31) * 4;
#pragma unroll
      for (int p = 0; p < 2; ++p) {
        float4 b4 = *(const float4*)&Bv[(size_t)(kb + k0 + r + p * 8) * DM + c];
        *(float4*)&Bs[r + p * 8][c] = b4;
      }
    }
    __syncthreads();
#pragma unroll
    for (int kk = 0; kk < BK; ++kk) {
      float4 a4 = *(const float4*)&As[kk][tm * 4];
      float4 b0 = *(const float4*)&Bs[kk][tn * 8];
      float4 b1 = *(const float4*)&Bs[kk][tn * 8 + 4];
      float a[4] = {a4.x, a4.y, a4.z, a4.w};
      float b[8] = {b0.x, b0.y, b0.z, b0.w, b1.x, b1.y, b1.z, b1.w};
#pragma unroll
      for (int i = 0; i < 4; ++i)
#pragma unroll
        for (int j = 0; j < 8; ++j) acc[i][j] = fmaf(a[i], b[j], acc[i][j]);
    }
    __syncthreads();
  }
#pragma unroll
  for (int i = 0; i < 4; ++i) {
    size_t off = ((size_t)split * ROWS + bm + tm * 4 + i) * DM + tn * 8;
    float4 o0 = {acc[i][0], acc[i][1], acc[i][2], acc[i][3]};
    float4 o1 = {acc[i][4], acc[i][5], acc[i][6], acc[i][7]};
    *(float4*)&part[off] = o0;
    *(float4*)&part[off + 4] = o1;
  }
}

// ---------------- reduce split-K partials + bias -> h0 ; fused rmsnorm -> u ----------------
__global__ __launch_bounds__(256) void reduce_rms_kernel(const float* __restrict__ part,
                                                         const float* __restrict__ b_emb,
                                                         const float* __restrict__ norm_w,
                                                         float* __restrict__ h0,
                                                         float* __restrict__ u) {
  int wave = threadIdx.x >> 6, lane = threadIdx.x & 63;
  int row = blockIdx.x * 4 + wave;
  float sx = 0.f, sy = 0.f;
#pragma unroll
  for (int sp = 0; sp < SPLITK; ++sp) {
    float2 v = *(const float2*)(part + ((size_t)sp * ROWS + row) * DM + 2 * lane);
    sx += v.x;
    sy += v.y;
  }
  float2 be = *(const float2*)(b_emb + 2 * lane);
  sx += be.x;
  sy += be.y;
  float2 hv = {sx, sy};
  *(float2*)(h0 + (size_t)row * DM + 2 * lane) = hv;
  float ss = sx * sx + sy * sy;
#pragma unroll
  for (int o = 32; o >= 1; o >>= 1) ss += __shfl_xor(ss, o);
  float rs = 1.f / sqrtf(ss * (1.f / 128.f) + 1e-5f);
  float2 wv = *(const float2*)(norm_w + 2 * lane);
  float2 o2 = {sx * rs * wv.x, sy * rs * wv.y};
  *(float2*)(u + (size_t)row * DM + 2 * lane) = o2;
}

// ---------------- generic tiled fp32 GEMM: C = A@B (+bias) ----------------
__global__ __launch_bounds__(256) void gemm_f32(const float* __restrict__ A,
                                                const float* __restrict__ Bv,
                                                const float* __restrict__ bias,
                                                float* __restrict__ C,
                                                int M, int N, int K) {
  constexpr int BM = 64, BN = 64, BK = 16;
  __shared__ float As[BK][BM + 4];
  __shared__ float Bs[BK][BN + 4];
  int tid = threadIdx.x;
  int tm = tid / 16, tn = tid % 16;
  int bm = blockIdx.y * BM, bn = blockIdx.x * BN;
  float acc[4][4] = {};
  for (int k0 = 0; k0 < K; k0 += BK) {
    for (int i = tid; i < BM * BK; i += 256) {
      int r = i / BK, c = i % BK;
      As[c][r] = A[(size_t)(bm + r) * K + k0 + c];
    }
    for (int i = tid; i < BK * BN; i += 256) {
      int r = i / BN, c = i % BN;
      Bs[r][c] = Bv[(size_t)(k0 + r) * N + bn + c];
    }
    __syncthreads();
#pragma unroll
    for (int kk = 0; kk < BK; ++kk) {
      float4 a4 = *(const float4*)&As[kk][tm * 4];
      float4 b4 = *(const float4*)&Bs[kk][tn * 4];
      float a[4] = {a4.x, a4.y, a4.z, a4.w};
      float b[4] = {b4.x, b4.y, b4.z, b4.w};
#pragma unroll
      for (int i = 0; i < 4; ++i)
#pragma unroll
        for (int j = 0; j < 4; ++j) acc[i][j] = fmaf(a[i], b[j], acc[i][j]);
    }
    __syncthreads();
  }
  float bb[4];
#pragma unroll
  for (int j = 0; j < 4; ++j) bb[j] = bias ? bias[bn + tn * 4 + j] : 0.f;
#pragma unroll
  for (int i = 0; i < 4; ++i) {
    int r = bm + tm * 4 + i;
    float4 o;
    o.x = acc[i][0] + bb[0];
    o.y = acc[i][1] + bb[1];
    o.z = acc[i][2] + bb[2];
    o.w = acc[i][3] + bb[3];
    *(float4*)&C[(size_t)r * N + bn + tn * 4] = o;
  }
}

// ---------------- causal depthwise conv (k=4) + bias + silu ----------------
__global__ __launch_bounds__(256) void conv_silu_kernel(const float* __restrict__ xz,
                                                        const float* __restrict__ conv_w,
                                                        const float* __restrict__ conv_b,
                                                        float* __restrict__ xs_row,
                                                        float* __restrict__ xs_T) {
  __shared__ float tile[64][65];
  __shared__ float cw[64][4];
  __shared__ float cb[64];
  int b = blockIdx.z, l0 = blockIdx.y * 64, c0 = blockIdx.x * 64;
  int tid = threadIdx.x;
  cw[tid / 4][tid % 4] = conv_w[(size_t)c0 * 4 + tid];
  if (tid < 64) cb[tid] = conv_b[c0 + tid];
  __syncthreads();
  int cl = tid % 64;
  int lbase = tid / 64;  // 0..3
#pragma unroll
  for (int i = 0; i < 16; ++i) {
    int ll = lbase + 4 * i;
    int l = l0 + ll;
    float acc = cb[cl];
#pragma unroll
    for (int k = 0; k < 4; ++k) {
      int li = l + k - 3;
      if (li >= 0) acc = fmaf(xz[((size_t)(b * L_ + li)) * 512 + c0 + cl], cw[cl][k], acc);
    }
    tile[ll][cl] = silu_f(acc);
  }
  __syncthreads();
  for (int i = tid; i < 4096; i += 256) {
    int lr = i / 64, c = i % 64;
    xs_row[((size_t)(b * L_ + l0 + lr)) * DI + c0 + c] = tile[lr][c];
  }
  for (int i = tid; i < 4096; i += 256) {
    int c = i / 64, lr = i % 64;
    xs_T[((size_t)(b * DI + c0 + c)) * L_ + l0 + lr] = tile[lr][c];
  }
}

// ---------------- dbl = xs @ W_x  (256 -> 40) ----------------
__global__ __launch_bounds__(256) void dbl_kernel(const float* __restrict__ xs_row,
                                                  const float* __restrict__ W_x,
                                                  float* __restrict__ dbl) {
  __shared__ float Xs[64][257];
  __shared__ float Wx[256 * 40];
  int tid = threadIdx.x;
  int r0 = blockIdx.x * 64;
  for (int i = tid; i < 64 * 256; i += 256) {
    int r = i >> 8, k = i & 255;
    Xs[r][k] = xs_row[(size_t)(r0 + r) * DI + k];
  }
  for (int i = tid; i < 256 * 40; i += 256) Wx[i] = W_x[i];
  __syncthreads();
  int r = tid & 63, q = tid >> 6;
  float acc[10] = {};
  for (int k = 0; k < 256; ++k) {
    float v = Xs[r][k];
#pragma unroll
    for (int j = 0; j < 10; ++j) acc[j] = fmaf(v, Wx[k * 40 + q * 10 + j], acc[j]);
  }
#pragma unroll
  for (int j = 0; j < 10; ++j) dbl[(size_t)(r0 + r) * 40 + q * 10 + j] = acc[j];
}

// ---------------- delta = softplus(dt @ W_dt + b_dt), stored transposed ----------------
__global__ __launch_bounds__(256) void delta_kernel(const float* __restrict__ dbl,
                                                    const float* __restrict__ W_dt,
                                                    const float* __restrict__ b_dt,
                                                    float* __restrict__ delta_T) {
  __shared__ float Tile[64][257];
  __shared__ float Dt[64][8];
  __shared__ float Wdt[8 * 256];
  int tid = threadIdx.x;
  int r0 = blockIdx.x * 64;
  int b = r0 / L_, l0 = r0 % L_;
  for (int i = tid; i < 64 * 8; i += 256) {
    int r = i >> 3, k = i & 7;
    Dt[r][k] = dbl[(size_t)(r0 + r) * 40 + k];
  }
  for (int i = tid; i < 8 * 256; i += 256) Wdt[i] = W_dt[i];
  __syncthreads();
  int c = tid;
  float bd = b_dt[c];
  for (int r = 0; r < 64; ++r) {
    float a = bd;
#pragma unroll
    for (int k = 0; k < 8; ++k) a = fmaf(Dt[r][k], Wdt[k * 256 + c], a);
    float sp = (a > 20.f) ? a : log1pf(__expf(a));
    Tile[r][c] = sp;
  }
  __syncthreads();
  for (int i = tid; i < 64 * 256; i += 256) {
    int cc = i >> 6, rr = i & 63;
    delta_T[((size_t)(b * DI + cc)) * L_ + l0 + rr] = Tile[rr][cc];
  }
}

// ---------------- chunked parallel selective scan ----------------
__global__ __launch_bounds__(512) void scan_kernel(const float* __restrict__ delta_T,
                                                   const float* __restrict__ xs_T,
                                                   const float* __restrict__ dbl,
                                                   const float* __restrict__ A_log,
                                                   float* __restrict__ y) {
  __shared__ float s_aprod[32][16];
  __shared__ float s_hend[32][16];
  __shared__ float s_hstart[32][16];
  int tid = threadIdx.x;
  int k = tid >> 4, s = tid & 15;   // chunk, state
  int g = blockIdx.x;               // b*256 + c
  int b = g >> 8, c = g & 255;
  float A = -__expf(A_log[c * DS + s]);
  const float* dp = delta_T + (size_t)g * L_ + k * 64;
  const float* xp = xs_T + (size_t)g * L_ + k * 64;
  const float* bp = dbl + ((size_t)(b * L_ + k * 64)) * 40 + 8 + s;
  const float* cp = dbl + ((size_t)(b * L_ + k * 64)) * 40 + 24 + s;

  float aprod = 1.f, h = 0.f;
  for (int j = 0; j < 64; j += 4) {
    float4 d4 = *(const float4*)(dp + j);
    float4 x4 = *(const float4*)(xp + j);
    float dj[4] = {d4.x, d4.y, d4.z, d4.w};
    float xj[4] = {x4.x, x4.y, x4.z, x4.w};
#pragma unroll
    for (int u = 0; u < 4; ++u) {
      float Bv = bp[(size_t)(j + u) * 40];
      float dA = __expf(dj[u] * A);
      aprod *= dA;
      h = fmaf(dA, h, dj[u] * Bv * xj[u]);
    }
  }
  s_aprod[k][s] = aprod;
  s_hend[k][s] = h;
  __syncthreads();

  if (tid < 16) {
    float hh = 0.f;
    for (int kk = 0; kk < 32; ++kk) {
      s_hstart[kk][tid] = hh;
      hh = fmaf(s_aprod[kk][tid], hh, s_hend[kk][tid]);
    }
  }
  __syncthreads();

  h = s_hstart[k][s];
  float* yp = y + ((size_t)(b * L_) + k * 64) * DI + c;
  for (int j = 0; j < 64; j += 4) {
    float4 d4 = *(const float4*)(dp + j);
    float4 x4 = *(const float4*)(xp + j);
    float dj[4] = {d4.x, d4.y, d4.z, d4.w};
    float xj[4] = {x4.x, x4.y, x4.z, x4.w};
#pragma unroll
    for (int u = 0; u < 4; ++u) {
      float Bv = bp[(size_t)(j + u) * 40];
      float Cv = cp[(size_t)(j + u) * 40];
      float dA = __expf(dj[u] * A);
      h = fmaf(dA, h, dj[u] * Bv * xj[u]);
      float p = h * Cv;
      p += __shfl_xor(p, 8, 16);
      p += __shfl_xor(p, 4, 16);
      p += __shfl_xor(p, 2, 16);
      p += __shfl_xor(p, 1, 16);
      if (s == 0) yp[(size_t)(j + u) * DI] = p;
    }
  }
}

// ---------------- y = (y + xs*Dp) * silu(res) ----------------
__global__ __launch_bounds__(256) void ypost_kernel(float* __restrict__ y,
                                                    const float* __restrict__ xs_row,
                                                    const float* __restrict__ xz,
                                                    const float* __restrict__ Dp) {
  int idx = (blockIdx.x * 256 + threadIdx.x) * 4;
  int row = idx >> 8, c = idx & 255;
  float4 yv = *(float4*)(y + idx);
  float4 xv = *(const float4*)(xs_row + idx);
  float4 rv = *(const float4*)(xz + (size_t)row * 512 + 256 + c);
  float4 dv = *(const float4*)(Dp + c);
  yv.x = (yv.x + xv.x * dv.x) * silu_f(rv.x);
  yv.y = (yv.y + xv.y * dv.y) * silu_f(rv.y);
  yv.z = (yv.z + xv.z * dv.z) * silu_f(rv.z);
  yv.w = (yv.w + xv.w * dv.w) * silu_f(rv.w);
  *(float4*)(y + idx) = yv;
}

// ---------------- final: ob = y@W_out; h=h0+ob; rmsnorm; head; softmax; argmax ----------------
__global__ __launch_bounds__(256) void final_kernel(const float* __restrict__ y,
                                                    const float* __restrict__ W_out,
                                                    const float* __restrict__ h0,
                                                    const float* __restrict__ normf_w,
                                                    const float* __restrict__ W_head,
                                                    const float* __restrict__ b_head,
                                                    float* __restrict__ pi_out,
                                                    float* __restrict__ pred_out) {
  __shared__ float Wl[256 * 128];
  __shared__ float Wh[128 * 6];
  int tid = threadIdx.x;
  for (int i = tid; i < 256 * 128; i += 256) Wl[i] = W_out[i];
  for (int i = tid; i < 768; i += 256) Wh[i] = W_head[i];
  __syncthreads();
  int wave = tid >> 6, lane = tid & 63;
  float nw0 = normf_w[2 * lane], nw1 = normf_w[2 * lane + 1];
  float bh[6];
#pragma unroll
  for (int j = 0; j < 6; ++j) bh[j] = b_head[j];
  for (int ri = 0; ri < 8; ++ri) {
    int row = blockIdx.x * 32 + wave * 8 + ri;
    float acc0 = 0.f, acc1 = 0.f;
    for (int k = 0; k < 256; k += 4) {
      float4 yv = *(const float4*)(y + (size_t)row * DI + k);
      float vj[4] = {yv.x, yv.y, yv.z, yv.w};
#pragma unroll
      for (int j = 0; j < 4; ++j) {
        float2 w = *(const float2*)&Wl[(k + j) * 128 + 2 * lane];
        acc0 = fmaf(vj[j], w.x, acc0);
        acc1 = fmaf(vj[j], w.y, acc1);
      }
    }
    float hv0 = h0[(size_t)row * DM + 2 * lane] + acc0;
    float hv1 = h0[(size_t)row * DM + 2 * lane + 1] + acc1;
    float ss = hv0 * hv0 + hv1 * hv1;
#pragma unroll
    for (int o = 32; o >= 1; o >>= 1) ss += __shfl_xor(ss, o);
    float rs = 1.f / sqrtf(ss * (1.f / 128.f) + 1e-5f);
    float f0 = hv0 * rs * nw0, f1 = hv1 * rs * nw1;
    float lg[6];
#pragma unroll
    for (int j = 0; j < 6; ++j)
      lg[j] = f0 * Wh[(2 * lane) * 6 + j] + f1 * Wh[(2 * lane + 1) * 6 + j];
#pragma unroll
    for (int j = 0; j < 6; ++j) {
#pragma unroll
      for (int o = 32; o >= 1; o >>= 1) lg[j] += __shfl_xor(lg[j], o);
      lg[j] += bh[j];
    }
    if (lane == 0) {
      float mv = lg[0];
      int am = 0;
#pragma unroll
      for (int j = 1; j < 6; ++j)
        if (lg[j] > mv) { mv = lg[j]; am = j; }
      float e[6], sum = 0.f;
#pragma unroll
      for (int j = 0; j < 6; ++j) { e[j] = __expf(lg[j] - mv); sum += e[j]; }
      float inv = 1.f / sum;
#pragma unroll
      for (int j = 0; j < 6; ++j) pi_out[(size_t)row * NL + j] = e[j] * inv;
      pred_out[row] = (float)am;
    }
  }
}

extern "C" void kernel_launch(void* const* d_in, const int* in_sizes, int n_in,
                              void* d_out, int out_size, void* d_ws, size_t ws_size,
                              hipStream_t stream) {
  const float* x = (const float*)d_in[0];
  const float* W_emb = (const float*)d_in[1];
  const float* b_emb = (const float*)d_in[2];
  const float* norm_w = (const float*)d_in[3];
  const float* W_in = (const float*)d_in[4];
  const float* conv_w = (const float*)d_in[5];
  const float* conv_b = (const float*)d_in[6];
  const float* W_x = (const float*)d_in[7];
  const float* W_dt = (const float*)d_in[8];
  const float* b_dt = (const float*)d_in[9];
  const float* A_log = (const float*)d_in[10];
  const float* Dp = (const float*)d_in[11];
  const float* W_out = (const float*)d_in[12];
  const float* normf_w = (const float*)d_in[13];
  const float* W_head = (const float*)d_in[14];
  const float* b_head = (const float*)d_in[15];

  float* ws = (float*)d_ws;
  float* h0 = ws;                      // 8192*128
  float* u = h0 + 1048576;             // 8192*128
  float* xz = u + 1048576;             // 8192*512
  float* xs_row = xz + 4194304;        // 8192*256
  float* xs_T = xs_row + 2097152;      // 1024*2048
  float* dbl = xs_T + 2097152;         // 8192*40
  float* delta_T = dbl + 327680;       // 1024*2048
  float* y = delta_T + 2097152;        // 8192*256

  // split-K partials (8*8192*128 = 8,388,608 floats) alias xz+xs_row+xs_T
  // (exactly 4,194,304+2,097,152+2,097,152) — dead before xz is written.
  float* part = xz;

  float* pi_out = (float*)d_out;
  float* pred_out = pi_out + (size_t)ROWS * NL;

  // 1) split-K emb GEMM -> partials
  gemm_emb_splitk<<<dim3(SPLITK, ROWS / 64), 256, 0, stream>>>(x, W_emb, part);
  // 2) reduce partials + bias -> h0; fused rmsnorm -> u
  reduce_rms_kernel<<<ROWS / 4, 256, 0, stream>>>(part, b_emb, norm_w, h0, u);
  // 3) xz = u @ W_in
  gemm_f32<<<dim3(8, 128), 256, 0, stream>>>(u, W_in, nullptr, xz, ROWS, 2 * DI, DM);
  // 4) xs = silu(causal_dwconv(xz[:, :256]))
  conv_silu_kernel<<<dim3(4, 32, 4), 256, 0, stream>>>(xz, conv_w, conv_b, xs_row, xs_T);
  // 5) dbl = xs @ W_x
  dbl_kernel<<<128, 256, 0, stream>>>(xs_row, W_x, dbl);
  // 6) delta = softplus(dt @ W_dt + b_dt)  (transposed store)
  delta_kernel<<<128, 256, 0, stream>>>(dbl, W_dt, b_dt, delta_T);
  // 7) chunked parallel selective scan
  scan_kernel<<<1024, 512, 0, stream>>>(delta_T, xs_T, dbl, A_log, y);
  // 8) y = (y + xs*Dp) * silu(res)
  ypost_kernel<<<2048, 256, 0, stream>>>(y, xs_row, xz, Dp);
  // 9) out GEMM + residual + rmsnorm + head + softmax + argmax
  final_kernel<<<256, 256, 0, stream>>>(y, W_out, h0, normf_w, W_head, b_head, pi_out, pred_out);
}

// Round 5
// 406.427 us; speedup vs baseline: 3.9947x; 1.1045x over previous
//
#include <hip/hip_runtime.h>
#include <hip/hip_bf16.h>
#include <math.h>

constexpr int B_ = 4, L_ = 2048, IN_DIM = 3072, DM = 128, DI = 256, DS = 16, NL = 6;
constexpr int ROWS = B_ * L_; // 8192
constexpr int SPLITK = 8, KC = IN_DIM / SPLITK; // 384

static __device__ __forceinline__ float silu_f(float x) {
  return x / (1.f + __expf(-x));
}

// ---------------- split-K embedding GEMM ----------------
// BM=64, BN=128 (full N), BK=32, 256 threads, 4x8 micro-tile.
// Column mapping: thread tn owns cols [tn*4, tn*4+3] and [64+tn*4, 64+tn*4+3]
// (lane stride 4 floats -> 2-way bank alias = free; stride 8 was 4-way).
__global__ __launch_bounds__(256) void gemm_emb_splitk(const float* __restrict__ A,
                                                       const float* __restrict__ Bv,
                                                       float* __restrict__ part) {
  constexpr int BM = 64, BK = 32;
  __shared__ float As[BK][BM + 4];
  __shared__ float Bs[BK][128 + 4];
  int split = blockIdx.x;          // 0..7
  int bm = blockIdx.y * BM;        // row block
  int kb = split * KC;
  int tid = threadIdx.x;
  int tm = tid >> 4, tn = tid & 15;
  float acc[4][8] = {};
  for (int k0 = 0; k0 < KC; k0 += BK) {
    // A tile 64x32: 512 float4, 2 per thread
#pragma unroll
    for (int p = 0; p < 2; ++p) {
      int i = tid + p * 256;
      int r = i >> 3, kq = (i & 7) * 4;
      float4 a4 = *(const float4*)&A[(size_t)(bm + r) * IN_DIM + kb + k0 + kq];
      As[kq + 0][r] = a4.x;
      As[kq + 1][r] = a4.y;
      As[kq + 2][r] = a4.z;
      As[kq + 3][r] = a4.w;
    }
    // B tile 32x128: 1024 float4, 4 per thread
#pragma unroll
    for (int p = 0; p < 4; ++p) {
      int i = tid + p * 256;
      int r = i >> 5, c = (i & 31) * 4;
      *(float4*)&Bs[r][c] = *(const float4*)&Bv[(size_t)(kb + k0 + r) * DM + c];
    }
    __syncthreads();
#pragma unroll
    for (int kk = 0; kk < BK; ++kk) {
      float4 a4 = *(const float4*)&As[kk][tm * 4];
      float4 b0 = *(const float4*)&Bs[kk][tn * 4];
      float4 b1 = *(const float4*)&Bs[kk][64 + tn * 4];
      float a[4] = {a4.x, a4.y, a4.z, a4.w};
      float b[8] = {b0.x, b0.y, b0.z, b0.w, b1.x, b1.y, b1.z, b1.w};
#pragma unroll
      for (int i = 0; i < 4; ++i)
#pragma unroll
        for (int j = 0; j < 8; ++j) acc[i][j] = fmaf(a[i], b[j], acc[i][j]);
    }
    __syncthreads();
  }
#pragma unroll
  for (int i = 0; i < 4; ++i) {
    size_t rowoff = ((size_t)split * ROWS + bm + tm * 4 + i) * DM;
    float4 o0 = {acc[i][0], acc[i][1], acc[i][2], acc[i][3]};
    float4 o1 = {acc[i][4], acc[i][5], acc[i][6], acc[i][7]};
    *(float4*)&part[rowoff + tn * 4] = o0;
    *(float4*)&part[rowoff + 64 + tn * 4] = o1;
  }
}

// ---------------- reduce split-K partials + bias -> h0 ; fused rmsnorm -> u ----------------
__global__ __launch_bounds__(256) void reduce_rms_kernel(const float* __restrict__ part,
                                                         const float* __restrict__ b_emb,
                                                         const float* __restrict__ norm_w,
                                                         float* __restrict__ h0,
                                                         float* __restrict__ u) {
  int wave = threadIdx.x >> 6, lane = threadIdx.x & 63;
  int row = blockIdx.x * 4 + wave;
  float sx = 0.f, sy = 0.f;
#pragma unroll
  for (int sp = 0; sp < SPLITK; ++sp) {
    float2 v = *(const float2*)(part + ((size_t)sp * ROWS + row) * DM + 2 * lane);
    sx += v.x;
    sy += v.y;
  }
  float2 be = *(const float2*)(b_emb + 2 * lane);
  sx += be.x;
  sy += be.y;
  float2 hv = {sx, sy};
  *(float2*)(h0 + (size_t)row * DM + 2 * lane) = hv;
  float ss = sx * sx + sy * sy;
#pragma unroll
  for (int o = 32; o >= 1; o >>= 1) ss += __shfl_xor(ss, o);
  float rs = 1.f / sqrtf(ss * (1.f / 128.f) + 1e-5f);
  float2 wv = *(const float2*)(norm_w + 2 * lane);
  float2 o2 = {sx * rs * wv.x, sy * rs * wv.y};
  *(float2*)(u + (size_t)row * DM + 2 * lane) = o2;
}

// ---------------- xz = u @ W_in : M=8192, K=128, N=512 ----------------
// BM=64, BN=128, BK=32, grid (4, 128)
__global__ __launch_bounds__(256) void gemm_in(const float* __restrict__ A,
                                               const float* __restrict__ Bv,
                                               float* __restrict__ C) {
  constexpr int BM = 64, BK = 32, N = 512;
  __shared__ float As[BK][BM + 4];
  __shared__ float Bs[BK][128 + 4];
  int bn = blockIdx.x * 128;
  int bm = blockIdx.y * BM;
  int tid = threadIdx.x;
  int tm = tid >> 4, tn = tid & 15;
  float acc[4][8] = {};
  for (int k0 = 0; k0 < DM; k0 += BK) {
#pragma unroll
    for (int p = 0; p < 2; ++p) {
      int i = tid + p * 256;
      int r = i >> 3, kq = (i & 7) * 4;
      float4 a4 = *(const float4*)&A[(size_t)(bm + r) * DM + k0 + kq];
      As[kq + 0][r] = a4.x;
      As[kq + 1][r] = a4.y;
      As[kq + 2][r] = a4.z;
      As[kq + 3][r] = a4.w;
    }
#pragma unroll
    for (int p = 0; p < 4; ++p) {
      int i = tid + p * 256;
      int r = i >> 5, c = (i & 31) * 4;
      *(float4*)&Bs[r][c] = *(const float4*)&Bv[(size_t)(k0 + r) * N + bn + c];
    }
    __syncthreads();
#pragma unroll
    for (int kk = 0; kk < BK; ++kk) {
      float4 a4 = *(const float4*)&As[kk][tm * 4];
      float4 b0 = *(const float4*)&Bs[kk][tn * 4];
      float4 b1 = *(const float4*)&Bs[kk][64 + tn * 4];
      float a[4] = {a4.x, a4.y, a4.z, a4.w};
      float b[8] = {b0.x, b0.y, b0.z, b0.w, b1.x, b1.y, b1.z, b1.w};
#pragma unroll
      for (int i = 0; i < 4; ++i)
#pragma unroll
        for (int j = 0; j < 8; ++j) acc[i][j] = fmaf(a[i], b[j], acc[i][j]);
    }
    __syncthreads();
  }
#pragma unroll
  for (int i = 0; i < 4; ++i) {
    size_t rowoff = (size_t)(bm + tm * 4 + i) * N + bn;
    float4 o0 = {acc[i][0], acc[i][1], acc[i][2], acc[i][3]};
    float4 o1 = {acc[i][4], acc[i][5], acc[i][6], acc[i][7]};
    *(float4*)&C[rowoff + tn * 4] = o0;
    *(float4*)&C[rowoff + 64 + tn * 4] = o1;
  }
}

// ---------------- causal depthwise conv (k=4) + bias + silu ----------------
__global__ __launch_bounds__(256) void conv_silu_kernel(const float* __restrict__ xz,
                                                        const float* __restrict__ conv_w,
                                                        const float* __restrict__ conv_b,
                                                        float* __restrict__ xs_row,
                                                        float* __restrict__ xs_T) {
  __shared__ float tile[64][65];
  __shared__ float cw[64][4];
  __shared__ float cb[64];
  int b = blockIdx.z, l0 = blockIdx.y * 64, c0 = blockIdx.x * 64;
  int tid = threadIdx.x;
  cw[tid / 4][tid % 4] = conv_w[(size_t)c0 * 4 + tid];
  if (tid < 64) cb[tid] = conv_b[c0 + tid];
  __syncthreads();
  int cl = tid % 64;
  int lbase = tid / 64;  // 0..3
#pragma unroll
  for (int i = 0; i < 16; ++i) {
    int ll = lbase + 4 * i;
    int l = l0 + ll;
    float acc = cb[cl];
#pragma unroll
    for (int k = 0; k < 4; ++k) {
      int li = l + k - 3;
      if (li >= 0) acc = fmaf(xz[((size_t)(b * L_ + li)) * 512 + c0 + cl], cw[cl][k], acc);
    }
    tile[ll][cl] = silu_f(acc);
  }
  __syncthreads();
  for (int i = tid; i < 4096; i += 256) {
    int lr = i / 64, c = i % 64;
    xs_row[((size_t)(b * L_ + l0 + lr)) * DI + c0 + c] = tile[lr][c];
  }
  for (int i = tid; i < 4096; i += 256) {
    int c = i / 64, lr = i % 64;
    xs_T[((size_t)(b * DI + c0 + c)) * L_ + l0 + lr] = tile[lr][c];
  }
}

// ---------------- dbl = xs @ W_x  (256 -> 40), 32 rows/block, grid 256 ----------------
__global__ __launch_bounds__(256) void dbl_kernel(const float* __restrict__ xs_row,
                                                  const float* __restrict__ W_x,
                                                  float* __restrict__ dbl) {
  __shared__ float Xs[32][257];
  __shared__ float Wx[256 * 40];
  int tid = threadIdx.x;
  int r0 = blockIdx.x * 32;
  for (int i = tid; i < 32 * 64; i += 256) {
    int r = i >> 6, kq = (i & 63) * 4;
    float4 v = *(const float4*)&xs_row[(size_t)(r0 + r) * DI + kq];
    Xs[r][kq + 0] = v.x;
    Xs[r][kq + 1] = v.y;
    Xs[r][kq + 2] = v.z;
    Xs[r][kq + 3] = v.w;
  }
  for (int i = tid; i < 256 * 40; i += 256) Wx[i] = W_x[i];
  __syncthreads();
  int r = tid & 31, q = tid >> 5;  // q in 0..7 -> output cols q*5..q*5+4
  float acc[5] = {};
  for (int k = 0; k < 256; ++k) {
    float v = Xs[r][k];
#pragma unroll
    for (int j = 0; j < 5; ++j) acc[j] = fmaf(v, Wx[k * 40 + q * 5 + j], acc[j]);
  }
#pragma unroll
  for (int j = 0; j < 5; ++j) dbl[(size_t)(r0 + r) * 40 + q * 5 + j] = acc[j];
}

// ---------------- delta = softplus(dt @ W_dt + b_dt), transposed, 32 rows/block ----------------
__global__ __launch_bounds__(256) void delta_kernel(const float* __restrict__ dbl,
                                                    const float* __restrict__ W_dt,
                                                    const float* __restrict__ b_dt,
                                                    float* __restrict__ delta_T) {
  __shared__ float Tile[32][257];
  __shared__ float Dt[32][8];
  __shared__ float Wdt[8 * 256];
  int tid = threadIdx.x;
  int r0 = blockIdx.x * 32;
  int b = r0 / L_, l0 = r0 % L_;
  if (tid < 256) {
    int r = tid >> 3, k = tid & 7;
    Dt[r][k] = dbl[(size_t)(r0 + r) * 40 + k];
  }
  for (int i = tid; i < 8 * 256; i += 256) Wdt[i] = W_dt[i];
  __syncthreads();
  int c = tid;
  float bd = b_dt[c];
  for (int r = 0; r < 32; ++r) {
    float a = bd;
#pragma unroll
    for (int k = 0; k < 8; ++k) a = fmaf(Dt[r][k], Wdt[k * 256 + c], a);
    float sp = (a > 20.f) ? a : log1pf(__expf(a));
    Tile[r][c] = sp;
  }
  __syncthreads();
  for (int i = tid; i < 32 * 256; i += 256) {
    int cc = i >> 5, rr = i & 31;
    delta_T[((size_t)(b * DI + cc)) * L_ + l0 + rr] = Tile[rr][cc];
  }
}

// ---------------- chunked parallel selective scan + fused ypost ----------------
__global__ __launch_bounds__(512) void scan_kernel(const float* __restrict__ delta_T,
                                                   const float* __restrict__ xs_T,
                                                   const float* __restrict__ dbl,
                                                   const float* __restrict__ A_log,
                                                   const float* __restrict__ Dp,
                                                   const float* __restrict__ xz,
                                                   float* __restrict__ y) {
  __shared__ float s_aprod[32][16];
  __shared__ float s_hend[32][16];
  __shared__ float s_hstart[32][16];
  int tid = threadIdx.x;
  int k = tid >> 4, s = tid & 15;   // chunk, state
  int g = blockIdx.x;               // b*256 + c
  int b = g >> 8, c = g & 255;
  float A = -__expf(A_log[c * DS + s]);
  float dpc = Dp[c];
  const float* dp = delta_T + (size_t)g * L_ + k * 64;
  const float* xp = xs_T + (size_t)g * L_ + k * 64;
  const float* bp = dbl + ((size_t)(b * L_ + k * 64)) * 40 + 8 + s;
  const float* cp = dbl + ((size_t)(b * L_ + k * 64)) * 40 + 24 + s;

  float aprod = 1.f, h = 0.f;
  for (int j = 0; j < 64; j += 4) {
    float4 d4 = *(const float4*)(dp + j);
    float4 x4 = *(const float4*)(xp + j);
    float dj[4] = {d4.x, d4.y, d4.z, d4.w};
    float xj[4] = {x4.x, x4.y, x4.z, x4.w};
#pragma unroll
    for (int u = 0; u < 4; ++u) {
      float Bv = bp[(size_t)(j + u) * 40];
      float dA = __expf(dj[u] * A);
      aprod *= dA;
      h = fmaf(dA, h, dj[u] * Bv * xj[u]);
    }
  }
  s_aprod[k][s] = aprod;
  s_hend[k][s] = h;
  __syncthreads();

  if (tid < 16) {
    float hh = 0.f;
    for (int kk = 0; kk < 32; ++kk) {
      s_hstart[kk][tid] = hh;
      hh = fmaf(s_aprod[kk][tid], hh, s_hend[kk][tid]);
    }
  }
  __syncthreads();

  h = s_hstart[k][s];
  float* yp = y + ((size_t)(b * L_) + k * 64) * DI + c;
  const float* rp = xz + ((size_t)(b * L_) + k * 64) * 512 + 256 + c;
  for (int j = 0; j < 64; j += 4) {
    float4 d4 = *(const float4*)(dp + j);
    float4 x4 = *(const float4*)(xp + j);
    float dj[4] = {d4.x, d4.y, d4.z, d4.w};
    float xj[4] = {x4.x, x4.y, x4.z, x4.w};
#pragma unroll
    for (int u = 0; u < 4; ++u) {
      float Bv = bp[(size_t)(j + u) * 40];
      float Cv = cp[(size_t)(j + u) * 40];
      float dA = __expf(dj[u] * A);
      h = fmaf(dA, h, dj[u] * Bv * xj[u]);
      float p = h * Cv;
      p += __shfl_xor(p, 8, 16);
      p += __shfl_xor(p, 4, 16);
      p += __shfl_xor(p, 2, 16);
      p += __shfl_xor(p, 1, 16);
      if (s == 0) {
        float res = rp[(size_t)(j + u) * 512];
        yp[(size_t)(j + u) * DI] = (p + xj[u] * dpc) * silu_f(res);
      }
    }
  }
}

// ---------------- final fused: ob = y@W_out; +h0; rmsnorm; head; softmax; argmax ----------------
// BM=32, BN=128 (full), BK=32, grid 256. Epilogue via 16-lane shuffles.
__global__ __launch_bounds__(256) void final_gemm_kernel(const float* __restrict__ y,
                                                         const float* __restrict__ W_out,
                                                         const float* __restrict__ h0,
                                                         const float* __restrict__ normf_w,
                                                         const float* __restrict__ W_head,
                                                         const float* __restrict__ b_head,
                                                         float* __restrict__ pi_out,
                                                         float* __restrict__ pred_out) {
  constexpr int BM = 32, BK = 32;
  __shared__ float As[BK][BM + 4];
  __shared__ float Bs[BK][128 + 4];
  __shared__ float Wh[128 * 6];
  int tid = threadIdx.x;
  int tm = tid >> 4, tn = tid & 15;
  int bm = blockIdx.x * BM;
  for (int i = tid; i < 768; i += 256) Wh[i] = W_head[i];
  float acc[2][8] = {};
  for (int k0 = 0; k0 < DI; k0 += BK) {
    // A tile 32x32: 256 float4, 1 per thread
    {
      int r = tid >> 3, kq = (tid & 7) * 4;
      float4 a4 = *(const float4*)&y[(size_t)(bm + r) * DI + k0 + kq];
      As[kq + 0][r] = a4.x;
      As[kq + 1][r] = a4.y;
      As[kq + 2][r] = a4.z;
      As[kq + 3][r] = a4.w;
    }
    // B tile 32x128: 1024 float4, 4 per thread
#pragma unroll
    for (int p = 0; p < 4; ++p) {
      int i = tid + p * 256;
      int r = i >> 5, c = (i & 31) * 4;
      *(float4*)&Bs[r][c] = *(const float4*)&W_out[(size_t)(k0 + r) * DM + c];
    }
    __syncthreads();
#pragma unroll
    for (int kk = 0; kk < BK; ++kk) {
      float a0 = As[kk][tm * 2], a1 = As[kk][tm * 2 + 1];
      float4 b0 = *(const float4*)&Bs[kk][tn * 4];
      float4 b1 = *(const float4*)&Bs[kk][64 + tn * 4];
      float b[8] = {b0.x, b0.y, b0.z, b0.w, b1.x, b1.y, b1.z, b1.w};
#pragma unroll
      for (int j = 0; j < 8; ++j) acc[0][j] = fmaf(a0, b[j], acc[0][j]);
#pragma unroll
      for (int j = 0; j < 8; ++j) acc[1][j] = fmaf(a1, b[j], acc[1][j]);
    }
    __syncthreads();
  }
  // epilogue: cols tn*4..+3 and 64+tn*4..+3
  float4 nwa = *(const float4*)&normf_w[tn * 4];
  float4 nwb = *(const float4*)&normf_w[64 + tn * 4];
  float nw[8] = {nwa.x, nwa.y, nwa.z, nwa.w, nwb.x, nwb.y, nwb.z, nwb.w};
  float bh[6];
#pragma unroll
  for (int j = 0; j < 6; ++j) bh[j] = b_head[j];
#pragma unroll
  for (int i = 0; i < 2; ++i) {
    int row = bm + tm * 2 + i;
    float4 h0a = *(const float4*)&h0[(size_t)row * DM + tn * 4];
    float4 h0b = *(const float4*)&h0[(size_t)row * DM + 64 + tn * 4];
    float hv[8] = {acc[i][0] + h0a.x, acc[i][1] + h0a.y, acc[i][2] + h0a.z, acc[i][3] + h0a.w,
                   acc[i][4] + h0b.x, acc[i][5] + h0b.y, acc[i][6] + h0b.z, acc[i][7] + h0b.w};
    float ss = 0.f;
#pragma unroll
    for (int j = 0; j < 8; ++j) ss += hv[j] * hv[j];
    ss += __shfl_xor(ss, 1);
    ss += __shfl_xor(ss, 2);
    ss += __shfl_xor(ss, 4);
    ss += __shfl_xor(ss, 8);
    float rs = 1.f / sqrtf(ss * (1.f / 128.f) + 1e-5f);
    float lg[6] = {};
#pragma unroll
    for (int j = 0; j < 8; ++j) {
      float fm = hv[j] * rs * nw[j];
      int col = (j < 4) ? (tn * 4 + j) : (64 + tn * 4 + (j - 4));
#pragma unroll
      for (int l = 0; l < 6; ++l) lg[l] = fmaf(fm, Wh[col * 6 + l], lg[l]);
    }
#pragma unroll
    for (int l = 0; l < 6; ++l) {
      lg[l] += __shfl_xor(lg[l], 1);
      lg[l] += __shfl_xor(lg[l], 2);
      lg[l] += __shfl_xor(lg[l], 4);
      lg[l] += __shfl_xor(lg[l], 8);
      lg[l] += bh[l];
    }
    if (tn == 0) {
      float mv = lg[0];
      int am = 0;
#pragma unroll
      for (int l = 1; l < 6; ++l)
        if (lg[l] > mv) { mv = lg[l]; am = l; }
      float e[6], sum = 0.f;
#pragma unroll
      for (int l = 0; l < 6; ++l) { e[l] = __expf(lg[l] - mv); sum += e[l]; }
      float inv = 1.f / sum;
#pragma unroll
      for (int l = 0; l < 6; ++l) pi_out[(size_t)row * NL + l] = e[l] * inv;
      pred_out[row] = (float)am;
    }
  }
}

extern "C" void kernel_launch(void* const* d_in, const int* in_sizes, int n_in,
                              void* d_out, int out_size, void* d_ws, size_t ws_size,
                              hipStream_t stream) {
  const float* x = (const float*)d_in[0];
  const float* W_emb = (const float*)d_in[1];
  const float* b_emb = (const float*)d_in[2];
  const float* norm_w = (const float*)d_in[3];
  const float* W_in = (const float*)d_in[4];
  const float* conv_w = (const float*)d_in[5];
  const float* conv_b = (const float*)d_in[6];
  const float* W_x = (const float*)d_in[7];
  const float* W_dt = (const float*)d_in[8];
  const float* b_dt = (const float*)d_in[9];
  const float* A_log = (const float*)d_in[10];
  const float* Dp = (const float*)d_in[11];
  const float* W_out = (const float*)d_in[12];
  const float* normf_w = (const float*)d_in[13];
  const float* W_head = (const float*)d_in[14];
  const float* b_head = (const float*)d_in[15];

  float* ws = (float*)d_ws;
  float* h0 = ws;                      // 8192*128
  float* u = h0 + 1048576;             // 8192*128
  float* xz = u + 1048576;             // 8192*512
  float* xs_row = xz + 4194304;        // 8192*256
  float* xs_T = xs_row + 2097152;      // 1024*2048
  float* dbl = xs_T + 2097152;         // 8192*40
  float* delta_T = dbl + 327680;       // 1024*2048
  float* y = delta_T + 2097152;        // 8192*256

  // split-K partials (8*8192*128 = 8,388,608 floats) alias xz+xs_row+xs_T —
  // dead before xz is written.
  float* part = xz;

  float* pi_out = (float*)d_out;
  float* pred_out = pi_out + (size_t)ROWS * NL;

  // 1) split-K emb GEMM -> partials
  gemm_emb_splitk<<<dim3(SPLITK, ROWS / 64), 256, 0, stream>>>(x, W_emb, part);
  // 2) reduce partials + bias -> h0; fused rmsnorm -> u
  reduce_rms_kernel<<<ROWS / 4, 256, 0, stream>>>(part, b_emb, norm_w, h0, u);
  // 3) xz = u @ W_in
  gemm_in<<<dim3(4, 128), 256, 0, stream>>>(u, W_in, xz);
  // 4) xs = silu(causal_dwconv(xz[:, :256]))
  conv_silu_kernel<<<dim3(4, 32, 4), 256, 0, stream>>>(xz, conv_w, conv_b, xs_row, xs_T);
  // 5) dbl = xs @ W_x
  dbl_kernel<<<256, 256, 0, stream>>>(xs_row, W_x, dbl);
  // 6) delta = softplus(dt @ W_dt + b_dt)  (transposed store)
  delta_kernel<<<256, 256, 0, stream>>>(dbl, W_dt, b_dt, delta_T);
  // 7) chunked parallel selective scan + fused ypost
  scan_kernel<<<1024, 512, 0, stream>>>(delta_T, xs_T, dbl, A_log, Dp, xz, y);
  // 8) final fused GEMM + residual + rmsnorm + head + softmax + argmax
  final_gemm_kernel<<<256, 256, 0, stream>>>(y, W_out, h0, normf_w, W_head, b_head, pi_out, pred_out);
}